// Round 1
// baseline (113.569 us; speedup 1.0000x reference)
//
#include <hip/hip_runtime.h>
#include <math.h>

// Problem constants (from reference)
#define BB 4
#define HH 512
#define WW 512
#define CC 32      // channels; 32 floats = 8 float4 = 128 B per point
#define HO 256
#define WO 256
// Output positions: BB*HO*WO = 262144; out_size = *CC = 8388608 floats

// Fill index grid with zeros (0 == empty). int4-vectorized.
__global__ void fill_zero_kernel(int4* __restrict__ g, int n4) {
    int i = blockIdx.x * blockDim.x + threadIdx.x;
    if (i < n4) g[i] = make_int4(0, 0, 0, 0);
}

// Scatter point index+1 into dense (B,H,W) int grid.
__global__ void scatter_idx_kernel(const int* __restrict__ coors,
                                   int* __restrict__ grid, int n) {
    int i = blockIdx.x * blockDim.x + threadIdx.x;
    if (i >= n) return;
    int b = coors[i * 3 + 0];
    int y = coors[i * 3 + 1];
    int x = coors[i * 3 + 2];
    grid[((size_t)b * HH + y) * WW + x] = i + 1;
}

// One thread per output position: gather <=9 window indices, max-reduce
// 32 channels in registers (8x float4), -inf -> 0 on store.
__global__ void __launch_bounds__(256)
pool_kernel(const float4* __restrict__ feat,   // N x 8 float4
            const int* __restrict__ grid,      // B*H*W
            float4* __restrict__ out) {        // B*HO*WO x 8 float4
    int pos = blockIdx.x * blockDim.x + threadIdx.x;
    if (pos >= BB * HO * WO) return;
    int ox = pos & (WO - 1);
    int t  = pos >> 8;          // / WO
    int oy = t & (HO - 1);
    int b  = t >> 8;            // / HO

    const float NEG = -INFINITY;
    float4 acc[8];
#pragma unroll
    for (int j = 0; j < 8; ++j) acc[j] = make_float4(NEG, NEG, NEG, NEG);

    int iy0 = 2 * oy - 1;
    int ix0 = 2 * ox - 1;
#pragma unroll
    for (int dy = 0; dy < 3; ++dy) {
        int iy = iy0 + dy;
        if (iy < 0 || iy >= HH) continue;
        const int* grow = grid + ((size_t)b * HH + iy) * WW;
#pragma unroll
        for (int dx = 0; dx < 3; ++dx) {
            int ix = ix0 + dx;
            if (ix < 0 || ix >= WW) continue;
            int idx = grow[ix];
            if (idx == 0) continue;
            const float4* f = feat + (size_t)(idx - 1) * 8;
#pragma unroll
            for (int j = 0; j < 8; ++j) {
                float4 v = f[j];
                acc[j].x = fmaxf(acc[j].x, v.x);
                acc[j].y = fmaxf(acc[j].y, v.y);
                acc[j].z = fmaxf(acc[j].z, v.z);
                acc[j].w = fmaxf(acc[j].w, v.w);
            }
        }
    }

    float4* o = out + (size_t)pos * 8;
#pragma unroll
    for (int j = 0; j < 8; ++j) {
        float4 v = acc[j];
        v.x = isinf(v.x) ? 0.0f : v.x;
        v.y = isinf(v.y) ? 0.0f : v.y;
        v.z = isinf(v.z) ? 0.0f : v.z;
        v.w = isinf(v.w) ? 0.0f : v.w;
        o[j] = v;
    }
}

extern "C" void kernel_launch(void* const* d_in, const int* in_sizes, int n_in,
                              void* d_out, int out_size, void* d_ws, size_t ws_size,
                              hipStream_t stream) {
    const float* features = (const float*)d_in[0];   // N x 32 fp32
    const int*   coors    = (const int*)d_in[1];     // N x 3 int32
    int n = in_sizes[0] / CC;                        // N = 300000

    int* grid = (int*)d_ws;                          // B*H*W int32 = 4 MiB

    // 1) zero the index grid (0xAA-poisoned every timed call)
    {
        int n4 = (BB * HH * WW) / 4;                 // 262144 int4
        int blk = 256, grd = (n4 + blk - 1) / blk;
        fill_zero_kernel<<<grd, blk, 0, stream>>>((int4*)grid, n4);
    }
    // 2) scatter indices
    {
        int blk = 256, grd = (n + blk - 1) / blk;
        scatter_idx_kernel<<<grd, blk, 0, stream>>>(coors, grid, n);
    }
    // 3) pool
    {
        int npos = BB * HO * WO;                     // 262144
        int blk = 256, grd = (npos + blk - 1) / blk;
        pool_kernel<<<grd, blk, 0, stream>>>((const float4*)features, grid,
                                             (float4*)d_out);
    }
}